// Round 1
// baseline (20743.118 us; speedup 1.0000x reference)
//
#include <hip/hip_runtime.h>
#include <hip/hip_bf16.h>
#include <math.h>

#define D 768
#define T 1024
#define BATCH 2
#define NH 12
#define NL 12
#define V 50257
#define NT 2048  // BATCH*T

// ---------------- wave helpers ----------------
__device__ inline float wave_reduce_sum(float v) {
  #pragma unroll
  for (int off = 32; off > 0; off >>= 1) v += __shfl_xor(v, off, 64);
  return v;
}
__device__ inline float wave_reduce_max(float v) {
  #pragma unroll
  for (int off = 32; off > 0; off >>= 1) v = fmaxf(v, __shfl_xor(v, off, 64));
  return v;
}

// ---------------- embedding ----------------
__global__ __launch_bounds__(256) void embed_kernel(const int* __restrict__ idx,
    const float* __restrict__ wte, const float* __restrict__ pos,
    float* __restrict__ x) {
  int row = blockIdx.x;                 // 0..NT-1
  int tok = idx[row];
  int tp  = row & (T - 1);
  const float* ws = wte + (size_t)tok * D;
  const float* ps = pos + (size_t)tp * D;
  float* xr = x + (size_t)row * D;
  for (int i = threadIdx.x; i < D; i += 256) xr[i] = ws[i] + ps[i];
}

// ---------------- layernorm ----------------
__global__ __launch_bounds__(256) void ln_kernel(const float* __restrict__ x,
    const float* __restrict__ g, const float* __restrict__ bta,
    float* __restrict__ y) {
  int row = blockIdx.x;
  const float* xr = x + (size_t)row * D;
  float* yr = y + (size_t)row * D;
  int t = threadIdx.x, lane = t & 63, wid = t >> 6;
  __shared__ float red[4];
  __shared__ float s_mean, s_rstd;

  float s = 0.f;
  for (int i = t; i < D; i += 256) s += xr[i];
  s = wave_reduce_sum(s);
  if (lane == 0) red[wid] = s;
  __syncthreads();
  if (t == 0) s_mean = (red[0] + red[1] + red[2] + red[3]) * (1.f / D);
  __syncthreads();
  float mean = s_mean;

  float v = 0.f;
  for (int i = t; i < D; i += 256) { float d = xr[i] - mean; v += d * d; }
  v = wave_reduce_sum(v);
  if (lane == 0) red[wid] = v;
  __syncthreads();
  if (t == 0) s_rstd = rsqrtf((red[0] + red[1] + red[2] + red[3]) * (1.f / D) + 1e-5f);
  __syncthreads();
  float rstd = s_rstd;

  for (int i = t; i < D; i += 256)
    yr[i] = (xr[i] - mean) * rstd * g[i] + bta[i];
}

// ---------------- attention (one wave per (b,h,q-row)) ----------------
__global__ __launch_bounds__(64) void attn_kernel(const float* __restrict__ qkv,
                                                  float* __restrict__ o) {
  const int tq   = blockIdx.x;
  const int h    = blockIdx.y;
  const int b    = blockIdx.z;
  const int lane = threadIdx.x;
  __shared__ float qs[64];
  __shared__ float s[T];
  const int RS = 3 * D;  // qkv row stride

  const float* qp = qkv + (size_t)(b * T + tq) * RS + h * 64;
  qs[lane] = qp[lane];
  __syncthreads();

  // scores (causal: keys 0..tq)
  for (int k = lane; k <= tq; k += 64) {
    const float* kp = qkv + (size_t)(b * T + k) * RS + D + h * 64;
    float acc = 0.f;
    #pragma unroll
    for (int d2 = 0; d2 < 64; ++d2) acc = fmaf(qs[d2], kp[d2], acc);
    s[k] = acc * 0.125f;  // 1/sqrt(64)
  }
  __syncthreads();

  float m = -1e30f;
  for (int k = lane; k <= tq; k += 64) m = fmaxf(m, s[k]);
  m = wave_reduce_max(m);
  float sum = 0.f;
  for (int k = lane; k <= tq; k += 64) { float p = expf(s[k] - m); s[k] = p; sum += p; }
  sum = wave_reduce_sum(sum);
  __syncthreads();
  float inv = 1.f / sum;

  // PV: lane owns output dim `lane`
  const float* vbase = qkv + (size_t)(b * T) * RS + 2 * D + h * 64 + lane;
  float acc = 0.f;
  for (int k = 0; k <= tq; ++k) acc = fmaf(s[k], vbase[(size_t)k * RS], acc);
  o[(size_t)(b * T + tq) * D + h * 64 + lane] = acc * inv;
}

// ---------------- fp32 tiled GEMM: C[M,N] = A[M,K] @ B(+epilogue) ----------------
// BT=false: B is [K,N] row-major. BT=true: B is [N,K] row-major (C = A @ B^T).
// bias (len N) and res (same shape as C) are optional via nullptr.
template <bool BT, bool GELU>
__global__ __launch_bounds__(256) void gemm_kernel(
    const float* __restrict__ A, const float* __restrict__ Bm,
    const float* __restrict__ bias, const float* __restrict__ res,
    float* __restrict__ C, int M, int N, int K) {
  __shared__ __align__(16) float As[16][128];
  __shared__ __align__(16) float Bs[16][128];
  const int t  = threadIdx.x;
  const int tx = t & 15, ty = t >> 4;
  const int m0 = blockIdx.y * 128, n0 = blockIdx.x * 128;

  float acc[8][8] = {};

  for (int k0 = 0; k0 < K; k0 += 16) {
    // A tile: 128 rows x 16 cols -> As[k][m] (transposed store)
    #pragma unroll
    for (int ff = 0; ff < 2; ++ff) {
      int f = t + ff * 256;
      int row = f >> 2, c4 = (f & 3) * 4;
      float4 a4 = *(const float4*)(A + (size_t)(m0 + row) * K + k0 + c4);
      As[c4 + 0][row] = a4.x; As[c4 + 1][row] = a4.y;
      As[c4 + 2][row] = a4.z; As[c4 + 3][row] = a4.w;
    }
    if (!BT) {
      // B tile: 16 rows x 128 cols (N multiple of 128 in all BT=false uses)
      #pragma unroll
      for (int ff = 0; ff < 2; ++ff) {
        int f = t + ff * 256;
        int row = f >> 5, c4 = (f & 31) * 4;
        *(float4*)&Bs[row][c4] = *(const float4*)(Bm + (size_t)(k0 + row) * N + n0 + c4);
      }
    } else {
      // B tile from [N,K]: row n has 16 contiguous k's; guard n
      #pragma unroll
      for (int ff = 0; ff < 2; ++ff) {
        int f = t + ff * 256;
        int n = f >> 2, c4 = (f & 3) * 4;
        float4 b4 = {0.f, 0.f, 0.f, 0.f};
        if (n0 + n < N) b4 = *(const float4*)(Bm + (size_t)(n0 + n) * K + k0 + c4);
        Bs[c4 + 0][n] = b4.x; Bs[c4 + 1][n] = b4.y;
        Bs[c4 + 2][n] = b4.z; Bs[c4 + 3][n] = b4.w;
      }
    }
    __syncthreads();

    #pragma unroll
    for (int kk = 0; kk < 16; ++kk) {
      float a[8], bb[8];
      *(float4*)&a[0]  = *(const float4*)&As[kk][ty * 8];
      *(float4*)&a[4]  = *(const float4*)&As[kk][ty * 8 + 4];
      *(float4*)&bb[0] = *(const float4*)&Bs[kk][tx * 8];
      *(float4*)&bb[4] = *(const float4*)&Bs[kk][tx * 8 + 4];
      #pragma unroll
      for (int i = 0; i < 8; ++i)
        #pragma unroll
        for (int j = 0; j < 8; ++j)
          acc[i][j] = fmaf(a[i], bb[j], acc[i][j]);
    }
    __syncthreads();
  }

  #pragma unroll
  for (int i = 0; i < 8; ++i) {
    int m = m0 + ty * 8 + i;
    #pragma unroll
    for (int j = 0; j < 8; ++j) {
      int n = n0 + tx * 8 + j;
      if (BT && n >= N) continue;
      float v2 = acc[i][j];
      if (bias) v2 += bias[n];
      if (res)  v2 += res[(size_t)m * N + n];
      if (GELU) v2 = 0.5f * v2 * (1.f + erff(v2 * 0.70710678118f));
      C[(size_t)m * N + n] = v2;
    }
  }
}

// ---------------- launcher ----------------
extern "C" void kernel_launch(void* const* d_in, const int* in_sizes, int n_in,
                              void* d_out, int out_size, void* d_ws, size_t ws_size,
                              hipStream_t stream) {
  const int*   idx   = (const int*)d_in[0];
  const float* wte   = (const float*)d_in[1];
  const float* pos   = (const float*)d_in[2];
  const float* ln1g  = (const float*)d_in[3];
  const float* ln1b  = (const float*)d_in[4];
  const float* qkvw  = (const float*)d_in[5];
  const float* qkvb  = (const float*)d_in[6];
  const float* projw = (const float*)d_in[7];
  const float* projb = (const float*)d_in[8];
  const float* ln2g  = (const float*)d_in[9];
  const float* ln2b  = (const float*)d_in[10];
  const float* fc1w  = (const float*)d_in[11];
  const float* fc1b  = (const float*)d_in[12];
  const float* fc2w  = (const float*)d_in[13];
  const float* fc2b  = (const float*)d_in[14];
  const float* lnfg  = (const float*)d_in[15];
  const float* lnfb  = (const float*)d_in[16];
  float* out = (float*)d_out;

  float* ws   = (float*)d_ws;
  float* x    = ws;                           // [NT, D]
  float* hbuf = x    + (size_t)NT * D;        // [NT, D]
  float* obuf = hbuf + (size_t)NT * D;        // [NT, D]
  float* big  = obuf + (size_t)NT * D;        // [NT, 4D] (also holds qkv [NT,3D])

  embed_kernel<<<NT, 256, 0, stream>>>(idx, wte, pos, x);

  for (int l = 0; l < NL; ++l) {
    // ln1
    ln_kernel<<<NT, 256, 0, stream>>>(x, ln1g + (size_t)l * D, ln1b + (size_t)l * D, hbuf);
    // qkv = h @ qkv_w + qkv_b   [NT, 3D]
    gemm_kernel<false, false><<<dim3((3 * D) / 128, NT / 128), 256, 0, stream>>>(
        hbuf, qkvw + (size_t)l * D * 3 * D, qkvb + (size_t)l * 3 * D, nullptr,
        big, NT, 3 * D, D);
    // attention
    attn_kernel<<<dim3(T, NH, BATCH), 64, 0, stream>>>(big, obuf);
    // x = x + o @ proj_w + proj_b
    gemm_kernel<false, false><<<dim3(D / 128, NT / 128), 256, 0, stream>>>(
        obuf, projw + (size_t)l * D * D, projb + (size_t)l * D, x,
        x, NT, D, D);
    // ln2
    ln_kernel<<<NT, 256, 0, stream>>>(x, ln2g + (size_t)l * D, ln2b + (size_t)l * D, hbuf);
    // fc1 + GELU -> big [NT, 4D]
    gemm_kernel<false, true><<<dim3((4 * D) / 128, NT / 128), 256, 0, stream>>>(
        hbuf, fc1w + (size_t)l * D * 4 * D, fc1b + (size_t)l * 4 * D, nullptr,
        big, NT, 4 * D, D);
    // x = x + gelu @ fc2_w + fc2_b
    gemm_kernel<false, false><<<dim3(D / 128, NT / 128), 256, 0, stream>>>(
        big, fc2w + (size_t)l * 4 * D * D, fc2b + (size_t)l * D, x,
        x, NT, D, 4 * D);
  }

  // final LN
  ln_kernel<<<NT, 256, 0, stream>>>(x, lnfg, lnfb, hbuf);
  // logits = h @ wte^T   [NT, V]
  gemm_kernel<true, false><<<dim3((V + 127) / 128, NT / 128), 256, 0, stream>>>(
      hbuf, wte, nullptr, nullptr, out, NT, V, D);
}